// Round 1
// baseline (2100.020 us; speedup 1.0000x reference)
//
#include <hip/hip_runtime.h>

#define H 65
#define G4 260            // 4*H gates
#define T_STEPS 1024
#define NPAIR 34          // half2 pairs per padded 65-vec (68 slots)
#define SLOTS 136         // halfs per xh buffer: input part 68 + hidden part 68
#define CHUNKS 17         // 16B chunks per buffer (136*2B/16B)

typedef _Float16 half_t;
typedef _Float16 half2_t __attribute__((ext_vector_type(2)));

static __device__ __forceinline__ float dot2(half2_t a, half2_t b, float c) {
#if __has_builtin(__builtin_amdgcn_fdot2)
  return __builtin_amdgcn_fdot2(a, b, c, false);
#else
  return c + (float)a[0] * (float)b[0] + (float)a[1] * (float)b[1];
#endif
}

static __device__ __forceinline__ float sigm(float v) {
  return 1.f / (1.f + __expf(-v));
}
// NaN-safe tanh: uses exp(-2|x|) <= 1 so no inf/inf
static __device__ __forceinline__ float tanh_act(float v) {
  float e = __expf(-2.f * fabsf(v));
  float t = (1.f - e) / (1.f + e);
  return v < 0.f ? -t : t;
}

// One block per batch row. Threads 0..259: layer-0 gate columns; 320..579:
// layer-1 gate columns; 580..639: x prefetch. Software pipeline: at superstep
// s, layer 0 computes t=s while layer 1 computes t=s-1 (both groups active).
__global__ __launch_bounds__(640, 1) void lstm_fused(
    const float* __restrict__ x,
    const float* __restrict__ wih0, const float* __restrict__ whh0,
    const float* __restrict__ bih0, const float* __restrict__ bhh0,
    const float* __restrict__ wih1, const float* __restrict__ whh1,
    const float* __restrict__ bih1, const float* __restrict__ bhh1,
    const float* __restrict__ wlin, const float* __restrict__ blin,
    float* __restrict__ out)
{
  __shared__ __align__(16) half_t xh0[SLOTS];  // [0..67]=x_t (padded), [68..135]=h0 (padded)
  __shared__ __align__(16) half_t xh1[SLOTS];  // [0..67]=h0_t,          [68..135]=h1
  __shared__ float g0a[G4];   // activated gates, layer 0
  __shared__ float g1a[G4];   // activated gates, layer 1
  __shared__ float h1f[H];    // final h1 (fp32) for output projection

  const int tid = threadIdx.x;
  const int b   = blockIdx.x;

  const bool isL0 = (tid < G4);
  const bool isL1 = (tid >= 320) && (tid < 320 + G4);
  const bool isCol = isL0 || isL1;
  const int  gcol = isL0 ? tid : (tid - 320);
  const bool isTanh = isCol && (gcol >= 2 * H) && (gcol < 3 * H);  // 'g' gate

  const bool isU0 = (tid < H);                       // layer-0 cell update, j=tid
  const bool isU1 = (tid >= 320) && (tid < 320 + H); // layer-1 cell update
  const int  uj   = isU0 ? tid : (tid - 320);

  const bool isLd = (tid >= 580);    // 60 loader threads
  const int  u    = tid - 580;

  // ---- load this thread's gate-column weights into registers (fp16 pairs) ----
  half2_t wc[2 * NPAIR];
  float bias = 0.f;
  if (isCol) {
    const float* wi = isL0 ? (wih0 + gcol * H) : (wih1 + gcol * H);
    const float* wh = isL0 ? (whh0 + gcol * H) : (whh1 + gcol * H);
    bias = isL0 ? (bih0[gcol] + bhh0[gcol]) : (bih1[gcol] + bhh1[gcol]);
#pragma unroll
    for (int p = 0; p < NPAIR; ++p) {
      int k0 = 2 * p, k1 = 2 * p + 1;
      float a  = (k0 < H) ? wi[k0] : 0.f;
      float bb = (k1 < H) ? wi[k1] : 0.f;
      half2_t v = {(half_t)a, (half_t)bb};
      wc[p] = v;
      float cc = (k0 < H) ? wh[k0] : 0.f;
      float dd = (k1 < H) ? wh[k1] : 0.f;
      half2_t v2 = {(half_t)cc, (half_t)dd};
      wc[NPAIR + p] = v2;
    }
  } else {
#pragma unroll
    for (int p = 0; p < 2 * NPAIR; ++p) {
      half2_t z = {(half_t)0.f, (half_t)0.f};
      wc[p] = z;
    }
  }

  // ---- zero LDS (pads stay zero forever; initial h,c = 0) ----
  for (int i = tid; i < SLOTS; i += 640) {
    xh0[i] = (half_t)0.f;
    xh1[i] = (half_t)0.f;
  }
  __syncthreads();

  // ---- prologue: x_0 -> LDS, x_1 -> regs (prefetch distance 2) ----
  const float* xrow = x + (size_t)b * (size_t)(T_STEPS * H);
  float nx0 = 0.f, nx1 = 0.f;
  if (isLd) {
    xh0[u] = (half_t)xrow[u];
    if (u < H - 60) xh0[60 + u] = (half_t)xrow[60 + u];
    nx0 = xrow[H + u];
    if (u < H - 60) nx1 = xrow[H + 60 + u];
  }
  __syncthreads();

  float c0 = 0.f, c1 = 0.f;  // cell states held by update threads

  for (int s = 0; s <= T_STEPS; ++s) {
    // ===== PHASE D: gate dot-products (+ x prefetch issue) =====
    float f0 = 0.f, f1 = 0.f;
    if (isLd && (s + 2 < T_STEPS)) {
      const float* xr = xrow + (size_t)(s + 2) * H;
      f0 = xr[u];
      if (u < H - 60) f1 = xr[60 + u];
    }
    if (isL0 && s < T_STEPS) {
      float a0 = bias, a1 = 0.f, a2 = 0.f, a3 = 0.f;
#pragma unroll
      for (int c = 0; c < CHUNKS; ++c) {
        uint4 q = *(const uint4*)&xh0[c * 8];
        a0 = dot2(__builtin_bit_cast(half2_t, q.x), wc[4 * c + 0], a0);
        a1 = dot2(__builtin_bit_cast(half2_t, q.y), wc[4 * c + 1], a1);
        a2 = dot2(__builtin_bit_cast(half2_t, q.z), wc[4 * c + 2], a2);
        a3 = dot2(__builtin_bit_cast(half2_t, q.w), wc[4 * c + 3], a3);
      }
      float g = (a0 + a1) + (a2 + a3);
      g0a[gcol] = isTanh ? tanh_act(g) : sigm(g);
    }
    if (isL1 && s >= 1) {
      float a0 = bias, a1 = 0.f, a2 = 0.f, a3 = 0.f;
#pragma unroll
      for (int c = 0; c < CHUNKS; ++c) {
        uint4 q = *(const uint4*)&xh1[c * 8];
        a0 = dot2(__builtin_bit_cast(half2_t, q.x), wc[4 * c + 0], a0);
        a1 = dot2(__builtin_bit_cast(half2_t, q.y), wc[4 * c + 1], a1);
        a2 = dot2(__builtin_bit_cast(half2_t, q.z), wc[4 * c + 2], a2);
        a3 = dot2(__builtin_bit_cast(half2_t, q.w), wc[4 * c + 3], a3);
      }
      float g = (a0 + a1) + (a2 + a3);
      g1a[gcol] = isTanh ? tanh_act(g) : sigm(g);
    }
    __syncthreads();

    // ===== PHASE U: cell/hidden update + stage next x =====
    if (isU0 && s < T_STEPS) {
      float iv = g0a[uj], fv = g0a[H + uj], gv = g0a[2 * H + uj], ov = g0a[3 * H + uj];
      c0 = fv * c0 + iv * gv;
      float h = ov * tanh_act(c0);
      half_t hh = (half_t)h;
      xh0[68 + uj] = hh;  // recurrent operand for layer 0
      xh1[uj]      = hh;  // input operand for layer 1
    }
    if (isU1 && s >= 1) {
      float iv = g1a[uj], fv = g1a[H + uj], gv = g1a[2 * H + uj], ov = g1a[3 * H + uj];
      c1 = fv * c1 + iv * gv;
      float h = ov * tanh_act(c1);
      xh1[68 + uj] = (half_t)h;
      if (s == T_STEPS) h1f[uj] = h;  // t = T-1: final hidden state
    }
    if (isLd && (s + 1 < T_STEPS)) {
      xh0[u] = (half_t)nx0;
      if (u < H - 60) xh0[60 + u] = (half_t)nx1;
    }
    nx0 = f0;
    nx1 = f1;
    __syncthreads();
  }

  // ---- output projection: out[b] = b_lin + h1_final . w_lin ----
  if (tid == 0) {
    float acc = blin[0];
    for (int j = 0; j < H; ++j) acc += h1f[j] * wlin[j];
    out[b] = acc;
  }
}

extern "C" void kernel_launch(void* const* d_in, const int* in_sizes, int n_in,
                              void* d_out, int out_size, void* d_ws, size_t ws_size,
                              hipStream_t stream) {
  const float* x    = (const float*)d_in[0];
  const float* wih0 = (const float*)d_in[1];
  const float* whh0 = (const float*)d_in[2];
  const float* bih0 = (const float*)d_in[3];
  const float* bhh0 = (const float*)d_in[4];
  const float* wih1 = (const float*)d_in[5];
  const float* whh1 = (const float*)d_in[6];
  const float* bih1 = (const float*)d_in[7];
  const float* bhh1 = (const float*)d_in[8];
  const float* wlin = (const float*)d_in[9];
  const float* blin = (const float*)d_in[10];
  float* out = (float*)d_out;

  lstm_fused<<<512, 640, 0, stream>>>(x, wih0, whh0, bih0, bhh0,
                                      wih1, whh1, bih1, bhh1, wlin, blin, out);
}